// Round 1
// baseline (1431.850 us; speedup 1.0000x reference)
//
#include <hip/hip_runtime.h>

// SubLinear: o[b,j] = sum_{i in segment j} x[b,i]*w[i] + bias[j]
// B=64, F=2^22, OUT=64. Memory-bound: 1.07 GB of x -> ~176us floor @6.3TB/s.
//
// R1 experiment: split uniform-chunk fast path and boundary-chunk slow path
// into SEPARATE kernels so the fast path's register allocation is not
// inflated by the slow path (occupancy), SPLITB 2->4 (4096 blocks, 16/CU),
// and nontemporal loads for the read-once x stream (no L2 allocate).
// If dur_us does not move, the measured time is harness poison traffic and
// the kernel is at its compulsory-traffic roofline.

#define TPB 256
#define CHUNK 4096   // features per block (= TPB * 4 floats * 4 k-steps)
#define BG 8         // batch rows per inner pass
#define SPLITB 4     // batch split across blocks

typedef float f32x4 __attribute__((ext_vector_type(4)));

__global__ __launch_bounds__(TPB) void init_out_kernel(const float* __restrict__ bias,
                                                       float* __restrict__ out,
                                                       int n, int outf) {
    int i = blockIdx.x * TPB + threadIdx.x;
    if (i < n) out[i] = bias[i % outf];
}

// ---------- uniform-chunk fast path (~97% of blocks) ----------
__global__ __launch_bounds__(TPB, 4) void sublinear_fast(
    const float* __restrict__ x,
    const float* __restrict__ w,
    const int*   __restrict__ seg,
    float*       __restrict__ out,
    int F, int B) {
    const int base = blockIdx.x * CHUNK;
    const int jLo  = seg[base];
    const int jHi  = seg[base + CHUNK - 1];
    if (jLo != jHi) return;                      // boundary chunk: other kernel

    const int tid      = threadIdx.x;
    const int lane     = tid & 63;
    const int rows     = B / SPLITB;             // 16
    const int rowStart = blockIdx.y * rows;

    f32x4 wreg[4];
#pragma unroll
    for (int k = 0; k < 4; ++k)
        wreg[k] = *(const f32x4*)(w + base + k * (TPB * 4) + tid * 4);

    const int j = jLo;
    for (int b0 = rowStart; b0 < rowStart + rows; b0 += BG) {
        float run[BG];
#pragma unroll
        for (int u = 0; u < BG; ++u) run[u] = 0.f;
#pragma unroll
        for (int k = 0; k < 4; ++k) {
            const int off = base + k * (TPB * 4) + tid * 4;
#pragma unroll
            for (int u = 0; u < BG; ++u) {
                f32x4 xv = __builtin_nontemporal_load(
                    (const f32x4*)(x + (size_t)(b0 + u) * F + off));
                run[u] += xv.x * wreg[k].x + xv.y * wreg[k].y +
                          xv.z * wreg[k].z + xv.w * wreg[k].w;
            }
        }
        // pairwise merge: 8 per-row partials -> row (b0 + (lane&7)) in one reg
        float m[4];
#pragma unroll
        for (int v = 0; v < 4; ++v) {
            float keep = (lane & 1) ? run[2 * v + 1] : run[2 * v];
            float send = (lane & 1) ? run[2 * v]     : run[2 * v + 1];
            m[v] = keep + __shfl_xor(send, 1, 64);
        }
        float n2[2];
#pragma unroll
        for (int v = 0; v < 2; ++v) {
            float keep = (lane & 2) ? m[2 * v + 1] : m[2 * v];
            float send = (lane & 2) ? m[2 * v]     : m[2 * v + 1];
            n2[v] = keep + __shfl_xor(send, 2, 64);
        }
        float p;
        {
            float keep = (lane & 4) ? n2[1] : n2[0];
            float send = (lane & 4) ? n2[0] : n2[1];
            p = keep + __shfl_xor(send, 4, 64);
        }
        p += __shfl_xor(p, 8, 64);
        p += __shfl_xor(p, 16, 64);
        p += __shfl_xor(p, 32, 64);
        if (lane < BG)
            atomicAdd(&out[(size_t)(b0 + lane) * 64 + j], p);
    }
}

// ---------- boundary-chunk slow path (~63 chunks x SPLITB blocks) ----------
__global__ __launch_bounds__(TPB) void sublinear_slow(
    const float* __restrict__ x,
    const float* __restrict__ w,
    const int*   __restrict__ seg,
    float*       __restrict__ out,
    int F, int B) {
    const int base = blockIdx.x * CHUNK;
    const int jLo  = seg[base];
    const int jHi  = seg[base + CHUNK - 1];
    if (jLo == jHi) return;                      // uniform chunk: other kernel

    const int tid      = threadIdx.x;
    const int rows     = B / SPLITB;             // 16
    const int rowStart = blockIdx.y * rows;

    float4 wreg[4];
#pragma unroll
    for (int k = 0; k < 4; ++k)
        wreg[k] = *(const float4*)(w + base + k * (TPB * 4) + tid * 4);

    __shared__ float acc[BG * 64];               // acc[u][j]
    int4 sreg[4];
#pragma unroll
    for (int k = 0; k < 4; ++k)
        sreg[k] = *(const int4*)(seg + base + k * (TPB * 4) + tid * 4);

    for (int b0 = rowStart; b0 < rowStart + rows; b0 += BG) {
#pragma unroll
        for (int t = 0; t < (BG * 64) / TPB; ++t) acc[tid + t * TPB] = 0.f;
        __syncthreads();

        float run[BG];
#pragma unroll
        for (int u = 0; u < BG; ++u) run[u] = 0.f;
        int cur = sreg[0].x;
#pragma unroll
        for (int k = 0; k < 4; ++k) {
            const int off = base + k * (TPB * 4) + tid * 4;
            float4 xv[BG];
#pragma unroll
            for (int u = 0; u < BG; ++u)
                xv[u] = *(const float4*)(x + (size_t)(b0 + u) * F + off);
            const int   sarr[4] = {sreg[k].x, sreg[k].y, sreg[k].z, sreg[k].w};
            const float warr[4] = {wreg[k].x, wreg[k].y, wreg[k].z, wreg[k].w};
#pragma unroll
            for (int c = 0; c < 4; ++c) {
                const int s = sarr[c];
                if (s != cur) {                  // segment transition: flush runs
#pragma unroll
                    for (int u = 0; u < BG; ++u) {
                        atomicAdd(&acc[u * 64 + cur], run[u]);
                        run[u] = 0.f;
                    }
                    cur = s;
                }
#pragma unroll
                for (int u = 0; u < BG; ++u)
                    run[u] += ((const float*)&xv[u])[c] * warr[c];
            }
        }
#pragma unroll
        for (int u = 0; u < BG; ++u) atomicAdd(&acc[u * 64 + cur], run[u]);
        __syncthreads();
#pragma unroll
        for (int t = 0; t < (BG * 64) / TPB; ++t) {
            const int idx = tid + t * TPB;
            const int u = idx >> 6, j = idx & 63;
            if (j >= jLo && j <= jHi)
                atomicAdd(&out[(size_t)(b0 + u) * 64 + j], acc[idx]);
        }
        __syncthreads();
    }
}

// Generic fallback for a non-multiple-of-CHUNK tail (not hit at F=2^22).
__global__ __launch_bounds__(TPB) void remainder_kernel(
    const float* __restrict__ x, const float* __restrict__ w,
    const int* __restrict__ seg, float* __restrict__ out,
    int F, int B, int start) {
    int i = start + blockIdx.x * TPB + threadIdx.x;
    if (i >= F) return;
    const float wv = w[i];
    const int   s  = seg[i];
    for (int b = 0; b < B; ++b)
        atomicAdd(&out[(size_t)b * 64 + s], x[(size_t)b * F + i] * wv);
}

extern "C" void kernel_launch(void* const* d_in, const int* in_sizes, int n_in,
                              void* d_out, int out_size, void* d_ws, size_t ws_size,
                              hipStream_t stream) {
    const float* x    = (const float*)d_in[0];
    const float* w    = (const float*)d_in[1];
    const float* bias = (const float*)d_in[2];
    const int*   seg  = (const int*)d_in[3];
    float*       out  = (float*)d_out;

    const int F    = in_sizes[1];            // 4194304
    const int B    = in_sizes[0] / F;        // 64
    const int OUTF = in_sizes[2];            // 64

    // d_out is re-poisoned before every call: materialize bias first.
    init_out_kernel<<<(out_size + TPB - 1) / TPB, TPB, 0, stream>>>(bias, out, out_size, OUTF);

    const int nChunks = F / CHUNK;           // 1024
    dim3 grid(nChunks, SPLITB);
    sublinear_fast<<<grid, TPB, 0, stream>>>(x, w, seg, out, F, B);
    sublinear_slow<<<grid, TPB, 0, stream>>>(x, w, seg, out, F, B);

    const int rem = F - nChunks * CHUNK;     // 0 for this shape
    if (rem > 0)
        remainder_kernel<<<(rem + TPB - 1) / TPB, TPB, 0, stream>>>(x, w, seg, out, F, B, nChunks * CHUNK);
}

// Round 2
// 1383.538 us; speedup vs baseline: 1.0349x; 1.0349x over previous
//
#include <hip/hip_runtime.h>

// SubLinear: o[b,j] = sum_{i in segment j} x[b,i]*w[i] + bias[j]
// B=64, F=2^22, OUT=64. Memory-bound: 1.07 GB of x -> ~176us floor @6.3TB/s.
//
// R2: pure-sequential streaming. One block = one (row, 8192-feature span):
// a single contiguous 32KB x read per block (no 16MB-strided multi-row
// streams, which alias HBM channels), w/seg spans come from L3 (16MB each,
// re-read per row). Uniform-span blocks (~94%) reduce ONE scalar via wave
// shuffles + 1 atomicAdd; boundary spans run-flush into LDS[64].

#define TPB 256
#define KSTEPS 8
#define CHUNK (TPB * 4 * KSTEPS)   // 8192 features = 32 KB per block
typedef float f32x4 __attribute__((ext_vector_type(4)));

__global__ __launch_bounds__(TPB) void init_out_kernel(const float* __restrict__ bias,
                                                       float* __restrict__ out,
                                                       int n, int outf) {
    int i = blockIdx.x * TPB + threadIdx.x;
    if (i < n) out[i] = bias[i % outf];
}

__global__ __launch_bounds__(TPB) void sublinear_kernel(
    const float* __restrict__ x,
    const float* __restrict__ w,
    const int*   __restrict__ seg,
    float*       __restrict__ out,
    int F) {
    const int base = blockIdx.x * CHUNK;
    const int row  = blockIdx.y;
    const int tid  = threadIdx.x;
    const size_t xb = (size_t)row * F + base;

    const int jLo = seg[base];
    const int jHi = seg[base + CHUNK - 1];

    if (jLo == jHi) {
        // ---------- uniform span (~94% of blocks): one dot-product ----------
        float acc = 0.f;
#pragma unroll
        for (int k = 0; k < KSTEPS; ++k) {
            const int off = k * (TPB * 4) + tid * 4;
            f32x4 xv = *(const f32x4*)(x + xb + off);
            f32x4 wv = *(const f32x4*)(w + base + off);
            acc += xv.x * wv.x + xv.y * wv.y + xv.z * wv.z + xv.w * wv.w;
        }
        acc += __shfl_xor(acc, 1, 64);
        acc += __shfl_xor(acc, 2, 64);
        acc += __shfl_xor(acc, 4, 64);
        acc += __shfl_xor(acc, 8, 64);
        acc += __shfl_xor(acc, 16, 64);
        acc += __shfl_xor(acc, 32, 64);
        if ((tid & 63) == 0)
            atomicAdd(&out[(size_t)row * 64 + jLo], acc);
    } else {
        // ---------- boundary span: per-thread run-flush into LDS[64] ----------
        __shared__ float acc[64];
        if (tid < 64) acc[tid] = 0.f;
        __syncthreads();

        float run = 0.f;
        int   cur = seg[base + tid * 4];
#pragma unroll
        for (int k = 0; k < KSTEPS; ++k) {
            const int off = k * (TPB * 4) + tid * 4;
            f32x4 xv = *(const f32x4*)(x + xb + off);
            f32x4 wv = *(const f32x4*)(w + base + off);
            int4  sv = *(const int4*)(seg + base + off);
            const int   sa[4] = {sv.x, sv.y, sv.z, sv.w};
            const float pa[4] = {xv.x * wv.x, xv.y * wv.y, xv.z * wv.z, xv.w * wv.w};
#pragma unroll
            for (int c = 0; c < 4; ++c) {
                if (sa[c] != cur) {          // segment transition: flush run
                    atomicAdd(&acc[cur], run);
                    run = 0.f;
                    cur = sa[c];
                }
                run += pa[c];
            }
        }
        atomicAdd(&acc[cur], run);
        __syncthreads();
        if (tid >= jLo && tid <= jHi)        // tid < 64 implied (jHi < 64)
            atomicAdd(&out[(size_t)row * 64 + tid], acc[tid]);
    }
}

// Generic fallback for a non-multiple-of-CHUNK tail (not hit at F=2^22).
__global__ __launch_bounds__(TPB) void remainder_kernel(
    const float* __restrict__ x, const float* __restrict__ w,
    const int* __restrict__ seg, float* __restrict__ out,
    int F, int B, int start) {
    int i = start + blockIdx.x * TPB + threadIdx.x;
    if (i >= F) return;
    const float wv = w[i];
    const int   s  = seg[i];
    for (int b = 0; b < B; ++b)
        atomicAdd(&out[(size_t)b * 64 + s], x[(size_t)b * F + i] * wv);
}

extern "C" void kernel_launch(void* const* d_in, const int* in_sizes, int n_in,
                              void* d_out, int out_size, void* d_ws, size_t ws_size,
                              hipStream_t stream) {
    const float* x    = (const float*)d_in[0];
    const float* w    = (const float*)d_in[1];
    const float* bias = (const float*)d_in[2];
    const int*   seg  = (const int*)d_in[3];
    float*       out  = (float*)d_out;

    const int F    = in_sizes[1];            // 4194304
    const int B    = in_sizes[0] / F;        // 64
    const int OUTF = in_sizes[2];            // 64

    // d_out is re-poisoned before every call: materialize bias first.
    init_out_kernel<<<(out_size + TPB - 1) / TPB, TPB, 0, stream>>>(bias, out, out_size, OUTF);

    const int nChunks = F / CHUNK;           // 512
    dim3 grid(nChunks, B);                   // 512 x 64 = 32768 blocks
    sublinear_kernel<<<grid, TPB, 0, stream>>>(x, w, seg, out, F);

    const int rem = F - nChunks * CHUNK;     // 0 for this shape
    if (rem > 0)
        remainder_kernel<<<(rem + TPB - 1) / TPB, TPB, 0, stream>>>(x, w, seg, out, F, B, nChunks * CHUNK);
}